// Round 13
// baseline (267.610 us; speedup 1.0000x reference)
//
#include <hip/hip_runtime.h>
#include <hip/hip_bf16.h>
#include <math.h>

#define B_  32
#define S_  512
#define D_  512
#define E_  8
#define H_  2048
#define O_  512

typedef __bf16 bf16x8 __attribute__((ext_vector_type(8)));
typedef float  f32x4  __attribute__((ext_vector_type(4)));

#define GL2LDS(src, dst) \
  __builtin_amdgcn_global_load_lds((const __attribute__((address_space(1))) void*)(src), \
                                   (__attribute__((address_space(3))) void*)(dst), 16, 0, 0)

#define MFMA16(a, b, c) __builtin_amdgcn_mfma_f32_16x16x32_bf16((a), (b), (c), 0, 0, 0)

// tanh-form GELU (proven r4-r12: absmax 3.9e-3 unchanged)
__device__ __forceinline__ float gelu_fast(float v) {
  float w = v * fmaf(v * v, 0.0713548162f, 1.5957691216f);
  float e = __expf(-w);
  return v * __builtin_amdgcn_rcpf(1.0f + e);
}

// =====================================================================
// Packed operand layout (r8/r9, HW-verified): [z][u = k/32][rows][64B],
// 16B slot within each 64B row pre-swizzled: phys_slot = ks ^ ((row>>1)&3).
// Any 2^k-row slice of one u-unit is contiguous.
// =====================================================================

// ---------------- cast x -> packed bf16 (xpack), fused attention scores ----
__global__ __launch_bounds__(256) void cast_score_kernel(
    const float* __restrict__ x, const float* __restrict__ attn_w,
    char* __restrict__ xpack, float* __restrict__ scores)
{
  const int t = threadIdx.x;
  const int r = t >> 5;
  const int cg = t & 31;
  const int row = blockIdx.x * 8 + r;     // global b*512+s
  const int bb = row >> 9, s = row & 511;
  const float* src  = x + (size_t)row * D_ + cg * 16;
  const float* wsrc = attn_w + cg * 16;
  char* xp = xpack + (size_t)bb * 524288 + s * 64;
  const int sx = (s >> 1) & 3;
  float acc = 0.f;
#pragma unroll
  for (int k = 0; k < 4; ++k) {
    const int d0 = cg * 16 + k * 4;
    float4 v  = *(const float4*)(src + k * 4);
    float4 wv = *(const float4*)(wsrc + k * 4);
    acc += v.x * wv.x + v.y * wv.y + v.z * wv.z + v.w * wv.w;
    ushort4 o;
    o.x = __builtin_bit_cast(unsigned short, __float2bfloat16(v.x));
    o.y = __builtin_bit_cast(unsigned short, __float2bfloat16(v.y));
    o.z = __builtin_bit_cast(unsigned short, __float2bfloat16(v.z));
    o.w = __builtin_bit_cast(unsigned short, __float2bfloat16(v.w));
    const int u = d0 >> 5;
    const int byte = u * 32768 + ((((d0 >> 3) & 3) ^ sx) << 4) + (d0 & 7) * 2;
    *(ushort4*)(xp + byte) = o;
  }
#pragma unroll
  for (int off = 16; off; off >>= 1) acc += __shfl_xor(acc, off);
  if (cg == 0) scores[row] = acc;
}

// ---------------- softmax over S per batch -> aw ----------------
__global__ __launch_bounds__(512) void softmax_aw_kernel(
    const float* __restrict__ scores, float* __restrict__ aw)
{
  __shared__ float red[8];
  __shared__ float mm, ss;
  const int t = threadIdx.x, b = blockIdx.x;
  float v = scores[b * S_ + t];
  float m = v;
#pragma unroll
  for (int off = 32; off; off >>= 1) m = fmaxf(m, __shfl_xor(m, off));
  if ((t & 63) == 0) red[t >> 6] = m;
  __syncthreads();
  if (t == 0) {
    float a = red[0];
    for (int i = 1; i < 8; ++i) a = fmaxf(a, red[i]);
    mm = a;
  }
  __syncthreads();
  float e = expf(v - mm);
  float s = e;
#pragma unroll
  for (int off = 32; off; off >>= 1) s += __shfl_xor(s, off);
  if ((t & 63) == 0) red[t >> 6] = s;
  __syncthreads();
  if (t == 0) {
    float a = 0.f;
    for (int i = 0; i < 8; ++i) a += red[i];
    ss = 1.f / a;
  }
  __syncthreads();
  aw[b * S_ + t] = e * ss;
}

// ---------------- pooled[b,d] = sum_s aw[b,s] * x[b,s,d] (f32, exact) ----------------
__global__ __launch_bounds__(512) void pool_kernel(
    const float* __restrict__ x, const float* __restrict__ aw, float* __restrict__ pooled)
{
  __shared__ float sm[4][128];
  const int t = threadIdx.x;
  const int dl = t & 127;
  const int sh = t >> 7;
  const int b = blockIdx.y;
  const int d = blockIdx.x * 128 + dl;
  const float* xp  = x + (size_t)b * S_ * D_ + d;
  const float* awb = aw + b * S_;
  float acc = 0.f;
#pragma unroll 4
  for (int s = sh; s < S_; s += 4)
    acc = fmaf(awb[s], xp[(size_t)s * D_], acc);
  if (sh) sm[sh][dl] = acc;
  __syncthreads();
  if (sh == 0) pooled[b * D_ + d] = acc + sm[1][dl] + sm[2][dl] + sm[3][dl];
}

// ---------------- gates + top-2 + renorm + expert-sort ----------------
__global__ __launch_bounds__(256) void gate_psort_kernel(
    const float* __restrict__ pooled, const float* __restrict__ gate_w,
    const float* __restrict__ gate_b, int* __restrict__ gidx, float* __restrict__ gwt,
    int* __restrict__ psort)
{
  __shared__ float gl[32][8];
  const int t = threadIdx.x;
  const int b = t >> 3, ee = t & 7;
  float z = gate_b[ee];
  const float* pb = pooled + b * D_;
  for (int d = 0; d < D_; ++d) z = fmaf(pb[d], gate_w[d * E_ + ee], z);
  gl[b][ee] = z;
  __syncthreads();
  if (t < 32) {
    float ge[8];
    float zmax = gl[t][0];
    for (int i = 1; i < 8; ++i) zmax = fmaxf(zmax, gl[t][i]);
    float zs = 0.f;
    for (int i = 0; i < 8; ++i) { ge[i] = expf(gl[t][i] - zmax); zs += ge[i]; }
    for (int i = 0; i < 8; ++i) ge[i] /= zs;
    int i0 = 0;
    for (int i = 1; i < 8; ++i) if (ge[i] > ge[i0]) i0 = i;
    int i1 = -1;
    for (int i = 0; i < 8; ++i) if (i != i0 && (i1 < 0 || ge[i] > ge[i1])) i1 = i;
    float denom = ge[i0] + ge[i1] + 1e-9f;
    gidx[t * 2 + 0] = i0; gidx[t * 2 + 1] = i1;
    gwt[t * 2 + 0] = ge[i0] / denom; gwt[t * 2 + 1] = ge[i1] / denom;
  }
  __syncthreads();
  if (t == 0) {
    int cnt[E_] = {}, pos[E_];
    for (int p = 0; p < 2 * B_; ++p) cnt[gidx[p]]++;
    int s = 0;
    for (int e2 = 0; e2 < E_; ++e2) { pos[e2] = s; s += cnt[e2]; }
    for (int p = 0; p < 2 * B_; ++p) psort[pos[gidx[p]]++] = p;
  }
}

// ---------------- weight pack: [z][R k][C rows] f32 -> packed bf16 ----------------
__global__ void pack_w_kernel(const float* __restrict__ in, char* __restrict__ outp,
                              int R, int C)
{
  __shared__ float tile[32][33];
  const int z = blockIdx.z;
  const float* inz = in + (size_t)z * R * C;
  const int c0 = blockIdx.x * 32, r0 = blockIdx.y * 32;
  const int tx = threadIdx.x, ty = threadIdx.y;
#pragma unroll
  for (int jj = 0; jj < 4; ++jj) {
    int r = r0 + ty + jj * 8;
    tile[ty + jj * 8][tx] = inz[(size_t)r * C + c0 + tx];
  }
  __syncthreads();
  const int k = r0 + tx;
  const int u = k >> 5;                                 // constant over tile
  const int PAN = C * 64;
  char* oz = outp + (size_t)z * R * C * 2 + (size_t)u * PAN;
  const int kslot = (k >> 3) & 3;
  const int kbyte = (k & 7) * 2;
#pragma unroll
  for (int jj = 0; jj < 4; ++jj) {
    const int row = c0 + ty + jj * 8;
    const int byte = row * 64 + ((kslot ^ ((row >> 1) & 3)) << 4) + kbyte;
    *(ushort*)(oz + byte) =
        __builtin_bit_cast(unsigned short, __float2bfloat16(tile[tx][ty + jj * 8]));
  }
}

// =====================================================================
// GEMM core v8: 256(A rows,m) x 128(B rows,n) x BK=64.
// 256 thr = 4 waves (wm=w>>1 m-half of 128 rows, wn=w&1 n-half of 64 rows),
// per-wave 128x64 output = acc[8][4] -> 24 ds_read_b128 per wave per tile
// for 64 MFMA (0.375 reads/MFMA, vs r12's 0.5 — the LDS unit was co-critical).
// SINGLE 48KB LDS buffer, m97 drain loop: {stage 12 contiguous GL2LDS |
// vmcnt(0) | barrier | 2x(12 reads + 32 MFMA) | barrier}; stall hiding from
// 2 resident blocks/CU (launch_bounds(256,2), 96KB LDS).
// LDS: A [2 kh][256 rows][64B] at 0 (32KB), B [2 kh][128 rows][64B] at 32K.
// Read swizzle phys_slot = ks ^ ((lr>>1)&3) (frag base rows mult of 16).
// =====================================================================
__device__ __forceinline__ void gemm_core_v8(const char* __restrict__ Ag, const char* __restrict__ Bg,
                                             const size_t unitA, const size_t unitB,
                                             const int NT, char* lds, f32x4 (&acc)[8][4])
{
  const int tid = threadIdx.x;
  const int l = tid & 63;
  const int w = tid >> 6;
  const int wm = w >> 1;                  // m-half: 128 A rows
  const int wn = w & 1;                   // n-half: 64 B rows
  const int lr = l & 15;
  const int ks = (l >> 4) & 3;
  const int swz = ((ks ^ ((lr >> 1) & 3)) << 4);
  const int abase = (wm * 128 + lr) * 64 + swz;           // + m*1024 + kh*16384
  const int bbase = 32768 + (wn * 64 + lr) * 64 + swz;    // + n*1024 + kh*8192
  const int dst = tid * 16;                               // 4KB per staging round

#pragma unroll 1
  for (int t = 0; t < NT; ++t) {
    const char* a0 = Ag + (size_t)(2 * t)     * unitA;
    const char* a1 = Ag + (size_t)(2 * t + 1) * unitA;
    const char* b0 = Bg + (size_t)(2 * t)     * unitB;
    const char* b1 = Bg + (size_t)(2 * t + 1) * unitB;
    // A kh0: 16KB contiguous
    GL2LDS(a0 + dst,          lds + dst);
    GL2LDS(a0 + 4096 + dst,   lds + 4096 + dst);
    GL2LDS(a0 + 8192 + dst,   lds + 8192 + dst);
    GL2LDS(a0 + 12288 + dst,  lds + 12288 + dst);
    // A kh1
    GL2LDS(a1 + dst,          lds + 16384 + dst);
    GL2LDS(a1 + 4096 + dst,   lds + 20480 + dst);
    GL2LDS(a1 + 8192 + dst,   lds + 24576 + dst);
    GL2LDS(a1 + 12288 + dst,  lds + 28672 + dst);
    // B kh0: 8KB
    GL2LDS(b0 + dst,          lds + 32768 + dst);
    GL2LDS(b0 + 4096 + dst,   lds + 36864 + dst);
    // B kh1
    GL2LDS(b1 + dst,          lds + 40960 + dst);
    GL2LDS(b1 + 4096 + dst,   lds + 45056 + dst);
    asm volatile("s_waitcnt vmcnt(0)" ::: "memory");
    __builtin_amdgcn_s_barrier();

#pragma unroll
    for (int kh = 0; kh < 2; ++kh) {
      bf16x8 af[8], bfv[4];
#pragma unroll
      for (int m = 0; m < 8; ++m)
        af[m] = *(const bf16x8*)(lds + kh * 16384 + abase + m * 1024);
#pragma unroll
      for (int n = 0; n < 4; ++n)
        bfv[n] = *(const bf16x8*)(lds + kh * 8192 + bbase + n * 1024);
#pragma unroll
      for (int m = 0; m < 8; ++m)
#pragma unroll
        for (int n = 0; n < 4; ++n)
          acc[m][n] = MFMA16(af[m], bfv[n], acc[m][n]);
    }
    __builtin_amdgcn_s_barrier();   // all reads done -> next stage may overwrite
  }
}

// ---------------- GEMM1: Hpack = gelu(x @ w1 + b1)  (A = W1 h-rows, BM=256) ----------------
__global__ __launch_bounds__(256, 2) void gemm1_kernel(
    const char* __restrict__ xpack, const char* __restrict__ W1pack,
    const float* __restrict__ b1, char* __restrict__ Hpack,
    const int* __restrict__ gidx, const int* __restrict__ psort)
{
  __shared__ char lds[49152];
  const int P = blockIdx.x;                 // 2048
  const int L = (P & 7) * 256 + (P >> 3);   // bijective XCD chunk remap
  const int p = psort[L >> 5];              // 32 tiles/pair, pair-clustered per XCD
  const int tl = L & 31;
  const int b = p >> 1;
  const int e = gidx[p];
  const int h0 = (tl >> 2) * 256;           // 8 h-tiles (m-axis)
  const int s0 = (tl & 3) * 128;            // 4 s-tiles (n-axis)
  const char* Ag = W1pack + (size_t)e * 2097152 + h0 * 64;  // unit stride 131072
  const char* Bg = xpack + (size_t)b * 524288 + s0 * 64;    // unit stride 32768
  f32x4 acc[8][4] = {};
  gemm_core_v8(Ag, Bg, 131072, 32768, D_ / 64, lds, acc);

  const int tid = threadIdx.x, l = tid & 63, w = tid >> 6;
  const int wm = w >> 1, wn = w & 1, lr = l & 15, q4 = ((l >> 4) & 3) << 2;
  const float* b1e = b1 + (size_t)e * H_ + h0;
  char* Hp = Hpack + (size_t)p * 2097152;
#pragma unroll
  for (int m = 0; m < 8; ++m) {
    const int hl = wm * 128 + m * 16 + q4;          // feature offset (mult of 4)
    const int h = h0 + hl;
    const int uh = h >> 5;
    const int hslot = (h >> 3) & 3;
    const int hbyte = (h & 7) * 2;
    const float4 bias = *(const float4*)(b1e + hl);
#pragma unroll
    for (int n = 0; n < 4; ++n) {
      const int sl = s0 + wn * 64 + n * 16 + lr;    // s row
      ushort4 ov;
      ov.x = __builtin_bit_cast(unsigned short, __float2bfloat16(gelu_fast(acc[m][n][0] + bias.x)));
      ov.y = __builtin_bit_cast(unsigned short, __float2bfloat16(gelu_fast(acc[m][n][1] + bias.y)));
      ov.z = __builtin_bit_cast(unsigned short, __float2bfloat16(gelu_fast(acc[m][n][2] + bias.z)));
      ov.w = __builtin_bit_cast(unsigned short, __float2bfloat16(gelu_fast(acc[m][n][3] + bias.w)));
      const int byte = uh * 32768 + sl * 64 + ((hslot ^ ((sl >> 1) & 3)) << 4) + hbyte;
      *(ushort4*)(Hp + byte) = ov;
    }
  }
}

// ---------------- GEMM2: out += gw * gelu(H @ w2 + b2)  (A = Hpack s-rows, BM=256) ----
// j along s, 16 lanes cover 16 consecutive o -> line-friendly atomics
// (r7/r12-verified: WRITE 65 MB). 2 deterministic f32 atomic terms per output.
__global__ __launch_bounds__(256, 2) void gemm2_kernel(
    const char* __restrict__ Hpack, const char* __restrict__ W2pack,
    const float* __restrict__ b2, float* __restrict__ out,
    const int* __restrict__ gidx, const float* __restrict__ gwt,
    const int* __restrict__ psort)
{
  __shared__ char lds[49152];
  const int P = blockIdx.x;                 // 512
  const int L = (P & 7) * 64 + (P >> 3);
  const int p = psort[L >> 3];              // 8 tiles/pair, expert-clustered per XCD
  const int tl = L & 7;
  const int b = p >> 1;
  const int e = gidx[p];
  const float gw = gwt[p];
  const int s0 = (tl >> 2) * 256;           // 2 s-tiles (m-axis)
  const int o0 = (tl & 3) * 128;            // 4 o-tiles (n-axis)
  const char* Ag = Hpack + (size_t)p * 2097152 + s0 * 64;   // unit stride 32768
  const char* Bg = W2pack + (size_t)e * 2097152 + o0 * 64;  // unit stride 32768
  f32x4 acc[8][4] = {};
  gemm_core_v8(Ag, Bg, 32768, 32768, H_ / 64, lds, acc);

  const int tid = threadIdx.x, l = tid & 63, w = tid >> 6;
  const int wm = w >> 1, wn = w & 1, lr = l & 15, q4 = ((l >> 4) & 3) << 2;
  const float* b2e = b2 + (size_t)e * O_ + o0;
#pragma unroll
  for (int m = 0; m < 8; ++m) {
    const int sl = s0 + wm * 128 + m * 16 + q4;     // s base for j=0..3
#pragma unroll
    for (int n = 0; n < 4; ++n) {
      const int ol = wn * 64 + n * 16 + lr;         // o (16 consecutive per lane group)
      const float bias = b2e[ol];
      float* dstp = out + ((size_t)b * S_ + sl) * O_ + o0 + ol;
#pragma unroll
      for (int j = 0; j < 4; ++j)
        atomicAdd(dstp + (size_t)j * O_, gelu_fast(acc[m][n][j] + bias) * gw);
    }
  }
}

// ---------------- sentinel (ws too small signal) ----------------
__global__ void sentinel_kernel(float* out, int n) {
  int i = blockIdx.x * blockDim.x + threadIdx.x;
  for (; i < n; i += gridDim.x * blockDim.x) out[i] = 1.0e6f;
}

extern "C" void kernel_launch(void* const* d_in, const int* in_sizes, int n_in,
                              void* d_out, int out_size, void* d_ws, size_t ws_size,
                              hipStream_t stream)
{
  const float* x      = (const float*)d_in[0];
  const float* attn_w = (const float*)d_in[1];
  // d_in[2] = attn_b: scalar, softmax-invariant -> unused
  const float* gate_w = (const float*)d_in[3];
  const float* gate_b = (const float*)d_in[4];
  const float* w1     = (const float*)d_in[5];
  const float* b1     = (const float*)d_in[6];
  const float* w2     = (const float*)d_in[7];
  const float* b2     = (const float*)d_in[8];
  float* out = (float*)d_out;

  char* ws = (char*)d_ws;
  const size_t OFF_GIDX = 0;
  const size_t OFF_GWT  = 256;
  const size_t OFF_PSRT = 512;
  const size_t OFF_X    = 1024;
  const size_t SZ_X     = (size_t)B_ * S_ * D_ * 2;   // 16 MB (xpack)
  const size_t OFF_W1T  = OFF_X + SZ_X;
  const size_t SZ_W1T   = (size_t)E_ * H_ * D_ * 2;   // 16 MB (W1pack)
  const size_t OFF_W2T  = OFF_W1T + SZ_W1T;
  const size_t SZ_W2T   = (size_t)E_ * O_ * H_ * 2;   // 16 MB (W2pack)
  const size_t OFF_H    = OFF_W2T + SZ_W2T;
  const size_t PAIR_H   = (size_t)S_ * H_ * 2;        // 2 MB per pair (Hpack)

  if (OFF_H + 64 * PAIR_H > ws_size) {
    hipLaunchKernelGGL(sentinel_kernel, dim3(256), dim3(256), 0, stream, out, out_size);
    return;
  }

  int*   gidx   = (int*)(ws + OFF_GIDX);
  float* gwt    = (float*)(ws + OFF_GWT);
  int*   psort  = (int*)(ws + OFF_PSRT);
  char*  xpack  = ws + OFF_X;
  char*  W1pack = ws + OFF_W1T;
  char*  W2pack = ws + OFF_W2T;
  char*  Hpack  = ws + OFF_H;
  // pool-chain scratch overlaid on Hpack region (consumed before gemm1 writes it)
  float* scores = (float*)(ws + OFF_H);            // 64 KB
  float* aw     = (float*)(ws + OFF_H + 65536);    // 64 KB
  float* pooled = (float*)(ws + OFF_H + 131072);   // 64 KB

  hipLaunchKernelGGL(cast_score_kernel, dim3(B_ * S_ / 8), dim3(256), 0, stream,
                     x, attn_w, xpack, scores);
  hipLaunchKernelGGL(softmax_aw_kernel, dim3(B_), dim3(512), 0, stream, scores, aw);
  hipLaunchKernelGGL(pool_kernel, dim3(4, B_), dim3(512), 0, stream, x, aw, pooled);
  hipLaunchKernelGGL(gate_psort_kernel, dim3(1), dim3(256), 0, stream,
                     pooled, gate_w, gate_b, gidx, gwt, psort);
  hipLaunchKernelGGL(pack_w_kernel, dim3(H_ / 32, D_ / 32, E_), dim3(32, 8), 0, stream,
                     w1, W1pack, D_, H_);
  hipLaunchKernelGGL(pack_w_kernel, dim3(O_ / 32, H_ / 32, E_), dim3(32, 8), 0, stream,
                     w2, W2pack, H_, O_);
  hipMemsetAsync(d_out, 0, (size_t)out_size * sizeof(float), stream);

  hipLaunchKernelGGL(gemm1_kernel, dim3(2048), dim3(256), 0, stream,
                     xpack, W1pack, b1, Hpack, gidx, psort);
  hipLaunchKernelGGL(gemm2_kernel, dim3(512), dim3(256), 0, stream,
                     Hpack, W2pack, b2, out, gidx, gwt, psort);
}

// Round 14
// 260.915 us; speedup vs baseline: 1.0257x; 1.0257x over previous
//
#include <hip/hip_runtime.h>
#include <hip/hip_bf16.h>
#include <math.h>

#define B_  32
#define S_  512
#define D_  512
#define E_  8
#define H_  2048
#define O_  512

typedef __bf16 bf16x8 __attribute__((ext_vector_type(8)));
typedef float  f32x4  __attribute__((ext_vector_type(4)));

#define GL2LDS(src, dst) \
  __builtin_amdgcn_global_load_lds((const __attribute__((address_space(1))) void*)(src), \
                                   (__attribute__((address_space(3))) void*)(dst), 16, 0, 0)

#define MFMA16(a, b, c) __builtin_amdgcn_mfma_f32_16x16x32_bf16((a), (b), (c), 0, 0, 0)

// tanh-form GELU (proven r4-r13: absmax 3.9e-3 unchanged)
__device__ __forceinline__ float gelu_fast(float v) {
  float w = v * fmaf(v * v, 0.0713548162f, 1.5957691216f);
  float e = __expf(-w);
  return v * __builtin_amdgcn_rcpf(1.0f + e);
}

// =====================================================================
// Packed operand layout (r8/r9, HW-verified): [z][u = k/32][rows][64B],
// 16B slot within each 64B row pre-swizzled: phys_slot = ks ^ ((row>>1)&3).
// A 128-row slice of one u-unit is contiguous 8 KB.
// =====================================================================

// ---------------- cast x -> packed bf16 (xpack), fused attention scores ----
__global__ __launch_bounds__(256) void cast_score_kernel(
    const float* __restrict__ x, const float* __restrict__ attn_w,
    char* __restrict__ xpack, float* __restrict__ scores)
{
  const int t = threadIdx.x;
  const int r = t >> 5;
  const int cg = t & 31;
  const int row = blockIdx.x * 8 + r;     // global b*512+s
  const int bb = row >> 9, s = row & 511;
  const float* src  = x + (size_t)row * D_ + cg * 16;
  const float* wsrc = attn_w + cg * 16;
  char* xp = xpack + (size_t)bb * 524288 + s * 64;
  const int sx = (s >> 1) & 3;
  float acc = 0.f;
#pragma unroll
  for (int k = 0; k < 4; ++k) {
    const int d0 = cg * 16 + k * 4;
    float4 v  = *(const float4*)(src + k * 4);
    float4 wv = *(const float4*)(wsrc + k * 4);
    acc += v.x * wv.x + v.y * wv.y + v.z * wv.z + v.w * wv.w;
    ushort4 o;
    o.x = __builtin_bit_cast(unsigned short, __float2bfloat16(v.x));
    o.y = __builtin_bit_cast(unsigned short, __float2bfloat16(v.y));
    o.z = __builtin_bit_cast(unsigned short, __float2bfloat16(v.z));
    o.w = __builtin_bit_cast(unsigned short, __float2bfloat16(v.w));
    const int u = d0 >> 5;
    const int byte = u * 32768 + ((((d0 >> 3) & 3) ^ sx) << 4) + (d0 & 7) * 2;
    *(ushort4*)(xp + byte) = o;
  }
#pragma unroll
  for (int off = 16; off; off >>= 1) acc += __shfl_xor(acc, off);
  if (cg == 0) scores[row] = acc;
}

// ---------------- softmax over S per batch -> aw ----------------
__global__ __launch_bounds__(512) void softmax_aw_kernel(
    const float* __restrict__ scores, float* __restrict__ aw)
{
  __shared__ float red[8];
  __shared__ float mm, ss;
  const int t = threadIdx.x, b = blockIdx.x;
  float v = scores[b * S_ + t];
  float m = v;
#pragma unroll
  for (int off = 32; off; off >>= 1) m = fmaxf(m, __shfl_xor(m, off));
  if ((t & 63) == 0) red[t >> 6] = m;
  __syncthreads();
  if (t == 0) {
    float a = red[0];
    for (int i = 1; i < 8; ++i) a = fmaxf(a, red[i]);
    mm = a;
  }
  __syncthreads();
  float e = expf(v - mm);
  float s = e;
#pragma unroll
  for (int off = 32; off; off >>= 1) s += __shfl_xor(s, off);
  if ((t & 63) == 0) red[t >> 6] = s;
  __syncthreads();
  if (t == 0) {
    float a = 0.f;
    for (int i = 0; i < 8; ++i) a += red[i];
    ss = 1.f / a;
  }
  __syncthreads();
  aw[b * S_ + t] = e * ss;
}

// ---------------- pooled[b,d] = sum_s aw[b,s] * x[b,s,d] (f32, exact) ----------------
__global__ __launch_bounds__(512) void pool_kernel(
    const float* __restrict__ x, const float* __restrict__ aw, float* __restrict__ pooled)
{
  __shared__ float sm[4][128];
  const int t = threadIdx.x;
  const int dl = t & 127;
  const int sh = t >> 7;
  const int b = blockIdx.y;
  const int d = blockIdx.x * 128 + dl;
  const float* xp  = x + (size_t)b * S_ * D_ + d;
  const float* awb = aw + b * S_;
  float acc = 0.f;
#pragma unroll 4
  for (int s = sh; s < S_; s += 4)
    acc = fmaf(awb[s], xp[(size_t)s * D_], acc);
  if (sh) sm[sh][dl] = acc;
  __syncthreads();
  if (sh == 0) pooled[b * D_ + d] = acc + sm[1][dl] + sm[2][dl] + sm[3][dl];
}

// ---------------- gates + top-2 + renorm + expert-sort ----------------
__global__ __launch_bounds__(256) void gate_psort_kernel(
    const float* __restrict__ pooled, const float* __restrict__ gate_w,
    const float* __restrict__ gate_b, int* __restrict__ gidx, float* __restrict__ gwt,
    int* __restrict__ psort)
{
  __shared__ float gl[32][8];
  const int t = threadIdx.x;
  const int b = t >> 3, ee = t & 7;
  float z = gate_b[ee];
  const float* pb = pooled + b * D_;
  for (int d = 0; d < D_; ++d) z = fmaf(pb[d], gate_w[d * E_ + ee], z);
  gl[b][ee] = z;
  __syncthreads();
  if (t < 32) {
    float ge[8];
    float zmax = gl[t][0];
    for (int i = 1; i < 8; ++i) zmax = fmaxf(zmax, gl[t][i]);
    float zs = 0.f;
    for (int i = 0; i < 8; ++i) { ge[i] = expf(gl[t][i] - zmax); zs += ge[i]; }
    for (int i = 0; i < 8; ++i) ge[i] /= zs;
    int i0 = 0;
    for (int i = 1; i < 8; ++i) if (ge[i] > ge[i0]) i0 = i;
    int i1 = -1;
    for (int i = 0; i < 8; ++i) if (i != i0 && (i1 < 0 || ge[i] > ge[i1])) i1 = i;
    float denom = ge[i0] + ge[i1] + 1e-9f;
    gidx[t * 2 + 0] = i0; gidx[t * 2 + 1] = i1;
    gwt[t * 2 + 0] = ge[i0] / denom; gwt[t * 2 + 1] = ge[i1] / denom;
  }
  __syncthreads();
  if (t == 0) {
    int cnt[E_] = {}, pos[E_];
    for (int p = 0; p < 2 * B_; ++p) cnt[gidx[p]]++;
    int s = 0;
    for (int e2 = 0; e2 < E_; ++e2) { pos[e2] = s; s += cnt[e2]; }
    for (int p = 0; p < 2 * B_; ++p) psort[pos[gidx[p]]++] = p;
  }
}

// ---------------- weight pack: [z][R k][C rows] f32 -> packed bf16 ----------------
__global__ void pack_w_kernel(const float* __restrict__ in, char* __restrict__ outp,
                              int R, int C)
{
  __shared__ float tile[32][33];
  const int z = blockIdx.z;
  const float* inz = in + (size_t)z * R * C;
  const int c0 = blockIdx.x * 32, r0 = blockIdx.y * 32;
  const int tx = threadIdx.x, ty = threadIdx.y;
#pragma unroll
  for (int jj = 0; jj < 4; ++jj) {
    int r = r0 + ty + jj * 8;
    tile[ty + jj * 8][tx] = inz[(size_t)r * C + c0 + tx];
  }
  __syncthreads();
  const int k = r0 + tx;
  const int u = k >> 5;                                 // constant over tile
  const int PAN = C * 64;
  char* oz = outp + (size_t)z * R * C * 2 + (size_t)u * PAN;
  const int kslot = (k >> 3) & 3;
  const int kbyte = (k & 7) * 2;
#pragma unroll
  for (int jj = 0; jj < 4; ++jj) {
    const int row = c0 + ty + jj * 8;
    const int byte = row * 64 + ((kslot ^ ((row >> 1) & 3)) << 4) + kbyte;
    *(ushort*)(oz + byte) =
        __builtin_bit_cast(unsigned short, __float2bfloat16(tile[tx][ty + jj * 8]));
  }
}

// =====================================================================
// GEMM core m97-style (r12, verified best): 128 x 128 x BK=64.
// 256 thr = 4 waves (wm=w>>1 m-half, wn=w&1 n-half), per-wave 64x64 acc[4][4].
// SINGLE 32KB LDS buffer, drain loop: {stage 8 GL2LDS | vmcnt(0) | barrier |
// 16 ds_reads + 32 MFMA | barrier}. Stall hiding from RESIDENT BLOCKS:
// r14 raises launch_bounds (256,3)->(256,4): 4 x 32KB = 128KB LDS, 16
// waves/CU. r12 measured: occ 36.5% @3 blocks -> 98us; r13 measured: occ
// 21.7% @2 blocks -> 109us. TLP is the dominant resource in this regime.
// =====================================================================
__device__ __forceinline__ void gemm_core_m97(const char* __restrict__ Ag, const char* __restrict__ Bg,
                                              const size_t unitA, const size_t unitB,
                                              const int NT, char* lds, f32x4 (&acc)[4][4])
{
  const int tid = threadIdx.x;
  const int l = tid & 63;
  const int w = tid >> 6;
  const int wm = w >> 1;
  const int wn = w & 1;
  const int lr = l & 15;
  const int ks = (l >> 4) & 3;
  const int swz = ((ks ^ ((lr >> 1) & 3)) << 4);
  const int abase = wm * 4096 + lr * 64 + swz;            // + m*1024 + kh*8192
  const int bbase = 16384 + wn * 4096 + lr * 64 + swz;    // + n*1024 + kh*8192
  const int dst = tid * 16;                               // 4KB per instruction round

#pragma unroll 1
  for (int t = 0; t < NT; ++t) {
    const char* a0 = Ag + (size_t)(2 * t)     * unitA;
    const char* a1 = Ag + (size_t)(2 * t + 1) * unitA;
    const char* b0 = Bg + (size_t)(2 * t)     * unitB;
    const char* b1 = Bg + (size_t)(2 * t + 1) * unitB;
    GL2LDS(a0 + dst, lds + dst);          GL2LDS(a0 + 4096 + dst, lds + 4096 + dst);
    GL2LDS(a1 + dst, lds + 8192 + dst);   GL2LDS(a1 + 4096 + dst, lds + 12288 + dst);
    GL2LDS(b0 + dst, lds + 16384 + dst);  GL2LDS(b0 + 4096 + dst, lds + 20480 + dst);
    GL2LDS(b1 + dst, lds + 24576 + dst);  GL2LDS(b1 + 4096 + dst, lds + 28672 + dst);
    asm volatile("s_waitcnt vmcnt(0)" ::: "memory");
    __builtin_amdgcn_s_barrier();

    bf16x8 a0f[4], a1f[4], b0f[4], b1f[4];
#pragma unroll
    for (int m = 0; m < 4; ++m) {
      a0f[m] = *(const bf16x8*)(lds + abase + m * 1024);
      a1f[m] = *(const bf16x8*)(lds + 8192 + abase + m * 1024);
    }
#pragma unroll
    for (int n = 0; n < 4; ++n) {
      b0f[n] = *(const bf16x8*)(lds + bbase + n * 1024);
      b1f[n] = *(const bf16x8*)(lds + 8192 + bbase + n * 1024);
    }
#pragma unroll
    for (int m = 0; m < 4; ++m)
#pragma unroll
      for (int n = 0; n < 4; ++n) {
        acc[m][n] = MFMA16(a0f[m], b0f[n], acc[m][n]);
        acc[m][n] = MFMA16(a1f[m], b1f[n], acc[m][n]);
      }
    __builtin_amdgcn_s_barrier();   // all reads done -> next stage may overwrite
  }
}

// ---------------- GEMM1: Hpack = gelu(x @ w1 + b1)  (A = W1 h-rows) ----------------
__global__ __launch_bounds__(256, 4) void gemm1_kernel(
    const char* __restrict__ xpack, const char* __restrict__ W1pack,
    const float* __restrict__ b1, char* __restrict__ Hpack,
    const int* __restrict__ gidx, const int* __restrict__ psort)
{
  __shared__ char lds[32768];
  const int P = blockIdx.x;                 // 4096
  const int L = (P & 7) * 512 + (P >> 3);   // bijective XCD chunk remap
  const int p = psort[L >> 6];              // 64 tiles/pair, pair-clustered per XCD
  const int tl = L & 63;
  const int b = p >> 1;
  const int e = gidx[p];
  const int h0 = (tl >> 2) * 128;           // 16 h-tiles
  const int s0 = (tl & 3) * 128;            // 4 s-tiles
  const char* Ag = W1pack + (size_t)e * 2097152 + h0 * 64;  // unit stride 131072
  const char* Bg = xpack + (size_t)b * 524288 + s0 * 64;    // unit stride 32768
  f32x4 acc[4][4] = {};
  gemm_core_m97(Ag, Bg, 131072, 32768, D_ / 64, lds, acc);

  const int tid = threadIdx.x, l = tid & 63, w = tid >> 6;
  const int wm = w >> 1, wn = w & 1, lr = l & 15, q4 = ((l >> 4) & 3) << 2;
  const float* b1e = b1 + (size_t)e * H_ + h0;
  char* Hp = Hpack + (size_t)p * 2097152;
#pragma unroll
  for (int m = 0; m < 4; ++m) {
    const int hl = wm * 64 + m * 16 + q4;           // feature offset (mult of 4)
    const int h = h0 + hl;
    const int uh = h >> 5;
    const int hslot = (h >> 3) & 3;
    const int hbyte = (h & 7) * 2;
    const float4 bias = *(const float4*)(b1e + hl);
#pragma unroll
    for (int n = 0; n < 4; ++n) {
      const int sl = s0 + wn * 64 + n * 16 + lr;    // s row
      ushort4 ov;
      ov.x = __builtin_bit_cast(unsigned short, __float2bfloat16(gelu_fast(acc[m][n][0] + bias.x)));
      ov.y = __builtin_bit_cast(unsigned short, __float2bfloat16(gelu_fast(acc[m][n][1] + bias.y)));
      ov.z = __builtin_bit_cast(unsigned short, __float2bfloat16(gelu_fast(acc[m][n][2] + bias.z)));
      ov.w = __builtin_bit_cast(unsigned short, __float2bfloat16(gelu_fast(acc[m][n][3] + bias.w)));
      const int byte = uh * 32768 + sl * 64 + ((hslot ^ ((sl >> 1) & 3)) << 4) + hbyte;
      *(ushort4*)(Hp + byte) = ov;
    }
  }
}

// ---------------- GEMM2: out += gw * gelu(H @ w2 + b2)  (A = Hpack s-rows) ----------------
// j along s, 16 lanes cover 16 consecutive o -> line-friendly atomics
// (r7/r12-verified: WRITE 65 MB). 2 deterministic f32 atomic terms per output.
__global__ __launch_bounds__(256, 4) void gemm2_kernel(
    const char* __restrict__ Hpack, const char* __restrict__ W2pack,
    const float* __restrict__ b2, float* __restrict__ out,
    const int* __restrict__ gidx, const float* __restrict__ gwt,
    const int* __restrict__ psort)
{
  __shared__ char lds[32768];
  const int P = blockIdx.x;                 // 1024
  const int L = (P & 7) * 128 + (P >> 3);
  const int p = psort[L >> 4];              // 16 tiles/pair, expert-clustered per XCD
  const int tl = L & 15;
  const int b = p >> 1;
  const int e = gidx[p];
  const float gw = gwt[p];
  const int o0 = (tl >> 2) * 128;           // 4 o-tiles (n-axis)
  const int s0 = (tl & 3) * 128;            // 4 s-tiles (m-axis)
  const char* Ag = Hpack + (size_t)p * 2097152 + s0 * 64;   // unit stride 32768
  const char* Bg = W2pack + (size_t)e * 2097152 + o0 * 64;  // unit stride 32768
  f32x4 acc[4][4] = {};
  gemm_core_m97(Ag, Bg, 32768, 32768, H_ / 64, lds, acc);

  const int tid = threadIdx.x, l = tid & 63, w = tid >> 6;
  const int wm = w >> 1, wn = w & 1, lr = l & 15, q4 = ((l >> 4) & 3) << 2;
  const float* b2e = b2 + (size_t)e * O_ + o0;
#pragma unroll
  for (int m = 0; m < 4; ++m) {
    const int sl = s0 + wm * 64 + m * 16 + q4;      // s base for j=0..3
#pragma unroll
    for (int n = 0; n < 4; ++n) {
      const int ol = wn * 64 + n * 16 + lr;         // o (16 consecutive per lane group)
      const float bias = b2e[ol];
      float* dstp = out + ((size_t)b * S_ + sl) * O_ + o0 + ol;
#pragma unroll
      for (int j = 0; j < 4; ++j)
        atomicAdd(dstp + (size_t)j * O_, gelu_fast(acc[m][n][j] + bias) * gw);
    }
  }
}

// ---------------- sentinel (ws too small signal) ----------------
__global__ void sentinel_kernel(float* out, int n) {
  int i = blockIdx.x * blockDim.x + threadIdx.x;
  for (; i < n; i += gridDim.x * blockDim.x) out[i] = 1.0e6f;
}

extern "C" void kernel_launch(void* const* d_in, const int* in_sizes, int n_in,
                              void* d_out, int out_size, void* d_ws, size_t ws_size,
                              hipStream_t stream)
{
  const float* x      = (const float*)d_in[0];
  const float* attn_w = (const float*)d_in[1];
  // d_in[2] = attn_b: scalar, softmax-invariant -> unused
  const float* gate_w = (const float*)d_in[3];
  const float* gate_b = (const float*)d_in[4];
  const float* w1     = (const float*)d_in[5];
  const float* b1     = (const float*)d_in[6];
  const float* w2     = (const float*)d_in[7];
  const float* b2     = (const float*)d_in[8];
  float* out = (float*)d_out;

  char* ws = (char*)d_ws;
  const size_t OFF_GIDX = 0;
  const size_t OFF_GWT  = 256;
  const size_t OFF_PSRT = 512;
  const size_t OFF_X    = 1024;
  const size_t SZ_X     = (size_t)B_ * S_ * D_ * 2;   // 16 MB (xpack)
  const size_t OFF_W1T  = OFF_X + SZ_X;
  const size_t SZ_W1T   = (size_t)E_ * H_ * D_ * 2;   // 16 MB (W1pack)
  const size_t OFF_W2T  = OFF_W1T + SZ_W1T;
  const size_t SZ_W2T   = (size_t)E_ * O_ * H_ * 2;   // 16 MB (W2pack)
  const size_t OFF_H    = OFF_W2T + SZ_W2T;
  const size_t PAIR_H   = (size_t)S_ * H_ * 2;        // 2 MB per pair (Hpack)

  if (OFF_H + 64 * PAIR_H > ws_size) {
    hipLaunchKernelGGL(sentinel_kernel, dim3(256), dim3(256), 0, stream, out, out_size);
    return;
  }

  int*   gidx   = (int*)(ws + OFF_GIDX);
  float* gwt    = (float*)(ws + OFF_GWT);
  int*   psort  = (int*)(ws + OFF_PSRT);
  char*  xpack  = ws + OFF_X;
  char*  W1pack = ws + OFF_W1T;
  char*  W2pack = ws + OFF_W2T;
  char*  Hpack  = ws + OFF_H;
  // pool-chain scratch overlaid on Hpack region (consumed before gemm1 writes it)
  float* scores = (float*)(ws + OFF_H);            // 64 KB
  float* aw     = (float*)(ws + OFF_H + 65536);    // 64 KB
  float* pooled = (float*)(ws + OFF_H + 131072);   // 64 KB

  hipLaunchKernelGGL(cast_score_kernel, dim3(B_ * S_ / 8), dim3(256), 0, stream,
                     x, attn_w, xpack, scores);
  hipLaunchKernelGGL(softmax_aw_kernel, dim3(B_), dim3(512), 0, stream, scores, aw);
  hipLaunchKernelGGL(pool_kernel, dim3(4, B_), dim3(512), 0, stream, x, aw, pooled);
  hipLaunchKernelGGL(gate_psort_kernel, dim3(1), dim3(256), 0, stream,
                     pooled, gate_w, gate_b, gidx, gwt, psort);
  hipLaunchKernelGGL(pack_w_kernel, dim3(H_ / 32, D_ / 32, E_), dim3(32, 8), 0, stream,
                     w1, W1pack, D_, H_);
  hipLaunchKernelGGL(pack_w_kernel, dim3(O_ / 32, H_ / 32, E_), dim3(32, 8), 0, stream,
                     w2, W2pack, H_, O_);
  hipMemsetAsync(d_out, 0, (size_t)out_size * sizeof(float), stream);

  hipLaunchKernelGGL(gemm1_kernel, dim3(4096), dim3(256), 0, stream,
                     xpack, W1pack, b1, Hpack, gidx, psort);
  hipLaunchKernelGGL(gemm2_kernel, dim3(1024), dim3(256), 0, stream,
                     Hpack, W2pack, b2, out, gidx, gwt, psort);
}